// Round 10
// baseline (358.920 us; speedup 1.0000x reference)
//
#include <hip/hip_runtime.h>
#include <hip/hip_bf16.h>

#define NPX 16384
typedef __attribute__((ext_vector_type(8))) short short8;
typedef __attribute__((ext_vector_type(8))) _Float16 half8;
typedef __attribute__((ext_vector_type(4))) _Float16 half4;
typedef __attribute__((ext_vector_type(4))) float f32x4;

#define DEV static __device__ __forceinline__

// wt layout (fp16 shorts), FRAGMENT-ORDERED:
// region-local idx = (cs*ET + t)*512 + lane*8 + kk
//   where e = t*16 + (lane&15), k = cs*32 + (lane>>4)*8 + kk
#define WAB   0        // E=64  K=64   ET=4
#define WINW  4096     // E=64  K=64   ET=4
#define W1T   8192     // E=128 K=64   ET=8
#define W2T   16384    // E=128 K=128  ET=8
#define W3T   32768    // E=64  K=128  ET=4
#define WQT   40960    // E=64  K=64   ET=4
#define WKV   45056    // E=128 K=64   ET=8
#define WTOT  53248
#define NBLK  1024u

DEV float lrelu(float v) { return v >= 0.f ? v : 0.01f * v; }
DEV short f2h(float f) { _Float16 h = (_Float16)f; return __builtin_bit_cast(short, h); }
DEV float h2f(short s) { return (float)__builtin_bit_cast(_Float16, s); }
DEV f32x4 mfmah(half8 a, half8 b, f32x4 c) {
    return __builtin_amdgcn_mfma_f32_16x16x32_f16(a, b, c, 0, 0, 0);
}

// device-scope grid barrier: arrival counter + fence (G16 recipe).
// Guard-capped spin so a residency surprise degrades to wrong-answer, not hang.
DEV void gridbar(unsigned* cnt)
{
    __syncthreads();
    if (threadIdx.x == 0) {
        __threadfence();
        atomicAdd(cnt, 1u);
        int guard = 0;
        while (atomicAdd(cnt, 0u) < NBLK && guard < (1 << 22)) {
            ++guard;
            __builtin_amdgcn_s_sleep(8);
        }
        __threadfence();
    }
    __syncthreads();
}

// ---------------------------------------------------------------------------
// M m-tiles (16 px each) GEMM: acc[m][t] += A[(m*16+row)][k] * W[t*16+col][k]
// A: LDS row-major, pitch shorts. WB: fragment-ordered global (ET == NT).
// ---------------------------------------------------------------------------
template<int K, int NT, int M>
DEV void gemmM(const short* __restrict__ A, int pitch,
               const short* __restrict__ WB, f32x4 (&acc)[M][NT])
{
    int lane = threadIdx.x & 63;
    int ln = lane & 15, q8 = (lane >> 4) * 8;
    const short* ap = A + (size_t)ln * pitch + q8;
    const short* bp = WB + lane * 8;
#pragma unroll
    for (int c0 = 0; c0 < K; c0 += 32) {
        half8 a[M];
#pragma unroll
        for (int m = 0; m < M; ++m)
            a[m] = *(const half8*)(ap + m * 16 * pitch + c0);
#pragma unroll
        for (int t = 0; t < NT; ++t) {
            half8 b = *(const half8*)(bp + (((c0 >> 5) * NT + t) << 9));
#pragma unroll
            for (int m = 0; m < M; ++m) acc[m][t] = mfmah(a[m], b, acc[m][t]);
        }
    }
}

template<int NT, int M>
DEV void acc_biasM(f32x4 (&acc)[M][NT], const float* __restrict__ bias)
{
    int ln = threadIdx.x & 15;
#pragma unroll
    for (int t = 0; t < NT; ++t) {
        float bv = bias[t * 16 + ln];
        f32x4 v = {bv, bv, bv, bv};
#pragma unroll
        for (int m = 0; m < M; ++m) acc[m][t] = v;
    }
}

// D layout: col=lane&15, row=(lane>>4)*4+reg -> LDS [m*16+row][pitch] fp16
template<int NT, int M>
DEV void dstoreM(const f32x4 (&acc)[M][NT], short* sD, int pitch)
{
    int lane = threadIdx.x & 63;
    int ln = lane & 15, r0 = (lane >> 4) * 4;
#pragma unroll
    for (int m = 0; m < M; ++m)
#pragma unroll
        for (int t = 0; t < NT; ++t)
#pragma unroll
            for (int r = 0; r < 4; ++r)
                sD[(m * 16 + r0 + r) * pitch + t * 16 + ln] = f2h(acc[m][t][r]);
}

// in-register LayerNorm(+lrelu) over 128 channels, per m-tile, fp32 stats
template<int NT, int M>
DEV void ln_regM(f32x4 (&acc)[M][NT], const float* __restrict__ g, const float* __restrict__ be)
{
    int lane = threadIdx.x & 63, ln = lane & 15;
#pragma unroll
    for (int m = 0; m < M; ++m) {
        f32x4 s = {0,0,0,0}, ss = {0,0,0,0};
#pragma unroll
        for (int t = 0; t < NT; ++t)
#pragma unroll
            for (int r = 0; r < 4; ++r) { float v = acc[m][t][r]; s[r] += v; ss[r] += v * v; }
#pragma unroll
        for (int off = 1; off < 16; off <<= 1)
#pragma unroll
            for (int r = 0; r < 4; ++r) {
                s[r] += __shfl_xor(s[r], off);
                ss[r] += __shfl_xor(ss[r], off);
            }
        f32x4 mm, rs;
#pragma unroll
        for (int r = 0; r < 4; ++r) {
            float mean = s[r] * (1.f / 128.f);
            float var = ss[r] * (1.f / 128.f) - mean * mean;
            mm[r] = mean; rs[r] = rsqrtf(var + 1e-5f);
        }
#pragma unroll
        for (int t = 0; t < NT; ++t) {
            float gg = g[t * 16 + ln], bb = be[t * 16 + ln];
#pragma unroll
            for (int r = 0; r < 4; ++r)
                acc[m][t][r] = lrelu((acc[m][t][r] - mm[r]) * rs[r] * gg + bb);
        }
    }
}

// ---------------------------------------------------------------------------
// k_all: fully fused kernel, normal launch + manual grid barriers.
// 1024 blocks x 256 thr = 4 blocks/CU x 256 CU (all co-resident:
// LDS 35840x4=143KB<=160KB, VGPR capped 128 by launch_bounds).
// Phase 0: weight prep                      | gridbar(cnt0)
// Phase M: r8 k_main, v/xm stay in LDS      | gridbar(cnt1)
// Phase O: softmax + wo-fold + PV + out
// Per-group LDS [8960 shorts]: X[32][72] | T[32][72] | H[32][136]
// ---------------------------------------------------------------------------
__global__ __launch_bounds__(256, 4) void k_all(const float* __restrict__ x,
                                                const float* __restrict__ sem,
                                                const float* __restrict__ wa,
                                                const float* __restrict__ ba,
                                                const float* __restrict__ wb,
                                                const float* __restrict__ bbv,
                                                const float* __restrict__ in_w,
                                                const float* __restrict__ in_b,
                                                const float* __restrict__ w1,
                                                const float* __restrict__ b1,
                                                const float* __restrict__ g1,
                                                const float* __restrict__ be1,
                                                const float* __restrict__ w2,
                                                const float* __restrict__ b2,
                                                const float* __restrict__ g2,
                                                const float* __restrict__ be2,
                                                const float* __restrict__ w3,
                                                const float* __restrict__ b3,
                                                const float* __restrict__ wq,
                                                const float* __restrict__ bq,
                                                const float* __restrict__ wk,
                                                const float* __restrict__ bk,
                                                const float* __restrict__ wv,
                                                const float* __restrict__ bv,
                                                const float* __restrict__ wo,
                                                const float* __restrict__ bo,
                                                const float* __restrict__ rescale,
                                                short* __restrict__ wt,
                                                float* __restrict__ gram,
                                                float* __restrict__ nsq,
                                                unsigned* __restrict__ cnt,
                                                float* __restrict__ out)
{
    __shared__ short blob[2][8960];
    const int tid = threadIdx.x, w = tid >> 6, lane = tid & 63;
    const int ln = lane & 15, qd = lane >> 4, r0 = qd * 4;
    const int g = w & 1, role = w >> 1;
    const int pw = blockIdx.x * 64 + g * 32;
    const int b = pw >> 14, n0 = pw & (NPX - 1);
    const float* xb = x + (size_t)b * 64 * NPX;
    short* X  = blob[g];            // [32][72] = 2304
    short* T  = blob[g] + 2304;     // [32][72] = 2304 ; v A-frags [0..2048) in phase M
    short* H  = blob[g] + 4608;     // [32][136] = 4352
    short* KT = X;                  // [64][32] = 2048 (after s2)
    float* scrH = (float*)H;        // qk[0..1024) qq[1024..1088)  (after q GEMM)
    float* scrK = (float*)(X + 2048); // kk[0..64)

    // ================= phase 0: weight prep =================
    {
        int idx = blockIdx.x * 256 + tid;
        if (idx < WTOT) {
            int base, ETl;
            if      (idx < WINW) { base = WAB;  ETl = 4; }
            else if (idx < W1T)  { base = WINW; ETl = 4; }
            else if (idx < W2T)  { base = W1T;  ETl = 8; }
            else if (idx < W3T)  { base = W2T;  ETl = 8; }
            else if (idx < WQT)  { base = W3T;  ETl = 4; }
            else if (idx < WKV)  { base = WQT;  ETl = 4; }
            else                 { base = WKV;  ETl = 8; }
            int i = idx - base;
            int frag = i >> 9, wi = i & 511;
            int lne = wi >> 3, kk = wi & 7;
            int lnn = lne & 15, qdd = lne >> 4;
            int cs = frag / ETl, t = frag % ETl;
            int e = t * 16 + lnn;
            int k = cs * 32 + qdd * 8 + kk;
            float v;
            if (base == WAB) {
                v = (e < 4) ? wa[k * 4 + e] : wb[((e - 4) / 3) * 192 + k * 3 + ((e - 4) % 3)];
            } else if (base == WINW) {
                v = in_w[k * 64 + e];
            } else if (base == W1T) {
                v = w1[k * 128 + e];
            } else if (base == W2T) {
                v = w2[k * 128 + e];
            } else if (base == W3T) {
                v = w3[k * 64 + e];
            } else if (base == WQT) {
                v = wq[k * 64 + e];
            } else {
                v = (e < 64) ? wk[k * 64 + e] : wv[k * 64 + (e - 64)];
            }
            wt[idx] = f2h(v);
        }
    }
    gridbar(cnt);      // wt visible device-wide; gram/nsq pre-zeroed by memset

    // ================= phase M: main (v/xm stay in LDS) ========
    {
        float vb[16];
#pragma unroll
        for (int t = 0; t < 16; ++t)
            vb[t] = xb[(size_t)(qd * 16 + t) * NPX + n0 + role * 16 + ln];
        short8 lo, hi;
#pragma unroll
        for (int t = 0; t < 8; ++t) { lo[t] = f2h(vb[t]); hi[t] = f2h(vb[8 + t]); }
        *reinterpret_cast<short8*>(&X[(role * 16 + ln) * 72 + qd * 16]) = lo;
        *reinterpret_cast<short8*>(&X[(role * 16 + ln) * 72 + qd * 16 + 8]) = hi;
    }
    __syncthreads();   // s1: X staged

    // ---- phase 1: both roles consume X ----
    f32x4 acc8[2][8];          // role0: h1/h2 accumulator
    if (role == 0) {
        acc_biasM<8, 2>(acc8, b1);
        gemmM<64, 8, 2>(X, 72, wt + W1T, acc8);
    } else {
        f32x4 a1f[2][4];
        {
            f32x4 z = {0,0,0,0};
#pragma unroll
            for (int m = 0; m < 2; ++m)
#pragma unroll
                for (int t = 0; t < 4; ++t) a1f[m][t] = z;
        }
        gemmM<64, 4, 2>(X, 72, wt + WAB, a1f);
#pragma unroll
        for (int t = 0; t < 4; ++t) {
            int j = t * 16 + ln;
            int cls = (j < 4) ? 0 : 1 + (j - 4) / 3;
            float bias = (j < 4) ? ba[j] : bbv[j - 4];
#pragma unroll
            for (int m = 0; m < 2; ++m) {
                f32x4 sm4 = *(const f32x4*)(sem + ((size_t)b * 21 + cls) * NPX + n0 + m * 16 + r0);
#pragma unroll
                for (int r = 0; r < 4; ++r)
                    T[(m * 16 + r0 + r) * 72 + j] = f2h(fmaxf(sm4[r], 0.f) * a1f[m][t][r] + bias);
            }
        }
    }
    __syncthreads();   // s2: X reads done everywhere -> KT may overwrite X

    // ---- phase 2: role-private pipelines ----
    f32x4 aqreg[2][4];         // role0: q result
    f32x4 a4xm[2][4];          // role0: xm result (lives until after s5)
    if (role == 0) {
        ln_regM<8, 2>(acc8, g1, be1);
        dstoreM<8, 2>(acc8, H, 136);
        acc_biasM<8, 2>(acc8, b2);
        gemmM<128, 8, 2>(H, 136, wt + W2T, acc8);
        ln_regM<8, 2>(acc8, g2, be2);
        dstoreM<8, 2>(acc8, H, 136);
        acc_biasM<4, 2>(a4xm, b3);
        gemmM<128, 4, 2>(H, 136, wt + W3T, a4xm);
        dstoreM<4, 2>(a4xm, H, 72);                  // xm tile for q GEMM
        acc_biasM<4, 2>(aqreg, bq);
        gemmM<64, 4, 2>(H, 72, wt + WQT, aqreg);
    } else {
        f32x4 a4[2][4];
        acc_biasM<4, 2>(a4, in_b);
        gemmM<64, 4, 2>(T, 72, wt + WINW, a4);
        dstoreM<4, 2>(a4, T, 72);                    // y overwrites feat
        f32x4 a3[2][8];
#pragma unroll
        for (int t = 0; t < 8; ++t) {
            float bvv = (t < 4) ? bk[t * 16 + ln] : bv[(t - 4) * 16 + ln];
            f32x4 vv = {bvv, bvv, bvv, bvv};
            a3[0][t] = vv; a3[1][t] = vv;
        }
        gemmM<64, 8, 2>(T, 72, wt + WKV, a3);
        // k -> KT (ch-major, LDS)
#pragma unroll
        for (int t = 0; t < 4; ++t)
#pragma unroll
            for (int m = 0; m < 2; ++m)
#pragma unroll
                for (int r = 0; r < 4; ++r)
                    KT[(t * 16 + ln) * 32 + m * 16 + r0 + r] = f2h(a3[m][t][r]);
        // v -> T in A-fragment order (STAYS IN LDS; consumed in phase O)
#pragma unroll
        for (int t = 4; t < 8; ++t)
#pragma unroll
            for (int m = 0; m < 2; ++m)
#pragma unroll
                for (int r = 0; r < 4; ++r)
                    T[m * 1024 + ((t - 4) >> 1) * 512 +
                      ((((t - 4) & 1) * 2 + (ln >> 3)) & 3) * 128 +
                      (r0 + r) * 8 + (ln & 7)] = f2h(a3[m][t][r]);
        // kk gram partial from regs -> scrK[0..64)
#pragma unroll
        for (int h = 0; h < 4; ++h) {
            f32x4 akk = {0, 0, 0, 0};
#pragma unroll
            for (int m = 0; m < 2; ++m) {
                half8 ka8 = {0, 0, 0, 0, 0, 0, 0, 0};
#pragma unroll
                for (int r = 0; r < 4; ++r) ka8[r] = (_Float16)a3[m][h][r];
                akk = mfmah(ka8, ka8, akk);
            }
#pragma unroll
            for (int r = 0; r < 4; ++r)
                if (ln == r0 + r) scrK[h * 16 + r0 + r] = akk[r];
        }
    }
    __syncthreads();   // s3: KT + kk done; role0's H reads done -> scrH writable

    // ---- phase 3: gram (role0; q from regs, k from KT) ----
    if (role == 0) {
#pragma unroll
        for (int h = 0; h < 4; ++h) {
            f32x4 aqk = {0,0,0,0}, aqq = {0,0,0,0};
#pragma unroll
            for (int m = 0; m < 2; ++m) {
                half4 kv4 = *(const half4*)(&KT[(h * 16 + ln) * 32 + m * 16 + r0]);
                half8 qa8 = {0, 0, 0, 0, 0, 0, 0, 0};
                half8 ka8 = {0, 0, 0, 0, 0, 0, 0, 0};
#pragma unroll
                for (int r = 0; r < 4; ++r) {
                    qa8[r] = (_Float16)aqreg[m][h][r];
                    ka8[r] = kv4[r];
                }
                aqk = mfmah(qa8, ka8, aqk);
                aqq = mfmah(qa8, qa8, aqq);
            }
#pragma unroll
            for (int r = 0; r < 4; ++r) {
                int d = r0 + r;
                scrH[h * 256 + d * 16 + ln] = aqk[r];
                if (ln == d) scrH[1024 + h * 16 + d] = aqq[r];
            }
        }
    }
    __syncthreads();   // s4: scratch complete

    // ---- cross-group reduce + device atomics ----
    {
        const float* h0 = (const float*)(blob[0] + 4608);
        const float* h1 = (const float*)(blob[1] + 4608);
        const float* k0 = (const float*)(blob[0] + 2048);
        const float* k1 = (const float*)(blob[1] + 2048);
#pragma unroll
        for (int i = 0; i < 4; ++i) {
            int idx = i * 256 + tid;
            atomicAdd(&gram[(size_t)b * 1024 + idx], h0[idx] + h1[idx]);
        }
        if (tid < 64) {
            atomicAdd(&nsq[b * 64 + tid], h0[1024 + tid] + h1[1024 + tid]);
        } else if (tid < 128) {
            int t2 = tid - 64;
            atomicAdd(&nsq[256 + b * 64 + t2], k0[t2] + k1[t2]);
        }
    }
    __syncthreads();   // s5: kk/scr reads done -> X writable
    if (role == 0) dstoreM<4, 2>(a4xm, X, 72);   // xm -> LDS X for phase O
    gridbar(cnt + 16); // all gram/nsq atomics visible; xm/v in LDS

    // ================= phase O: softmax + fold wo + PV + residual ==========
    float* s_at = (float*)(blob[1] + 4608);   // 1024 f32 (group1 H, dead)
    short* mtl  = blob[0] + 4608;             // 4096 sh  (group0 H, dead)

    // phase A: softmax (64 threads)
    if (tid < 64) {
        int h = tid >> 4, d = tid & 15;
        float nq = sqrtf(nsq[b * 64 + h * 16 + d]) + 1e-8f;
        float rsc = rescale[h];
        float lg[16];
#pragma unroll
        for (int e = 0; e < 16; ++e) {
            float nk = sqrtf(nsq[256 + b * 64 + h * 16 + e]) + 1e-8f;
            lg[e] = rsc * gram[b * 1024 + h * 256 + d * 16 + e] / (nq * nk);
        }
        float m = lg[0];
#pragma unroll
        for (int e = 1; e < 16; ++e) m = fmaxf(m, lg[e]);
        float ssum = 0.f;
#pragma unroll
        for (int e = 0; e < 16; ++e) { lg[e] = expf(lg[e] - m); ssum += lg[e]; }
        float inv = 1.f / ssum;
#pragma unroll
        for (int e = 0; e < 16; ++e) s_at[h * 256 + d * 16 + e] = lg[e] * inv;
    }
    __syncthreads();

    // phase B: fold wo -> mtl (B-fragment layout)
    {
        int he = tid >> 2, h = he >> 4, e = he & 15;
        int cc0 = (tid & 3) * 16;
        int mbase = (he >> 5) * 2048 + ((he >> 3) & 3) * 128 + (he & 7);
#pragma unroll
        for (int cx = 0; cx < 16; ++cx) {
            int cc = cc0 + cx;
            float s = 0.f;
#pragma unroll
            for (int d = 0; d < 16; ++d)
                s = fmaf(s_at[h * 256 + d * 16 + e], wo[(h * 16 + d) * 64 + cc], s);
            mtl[mbase + (cc >> 4) * 512 + (cc & 15) * 8] = f2h(s);
        }
    }
    __syncthreads();

    // phase C: PV + residual + out (per wave: its own 16-px tile, all LDS)
    {
        int gC = w >> 1, mC = w & 1;
        int pwC = blockIdx.x * 64 + w * 16;
        int n0C = pwC & (NPX - 1);
        const short* apl = blob[gC] + 2304 + mC * 1024;   // v A-frags in T
        const short* Xg  = blob[gC];                      // xm [32][72]
        f32x4 acc[4];
#pragma unroll
        for (int t = 0; t < 4; ++t) {
            float bvv = bo[t * 16 + ln];
            f32x4 v = {bvv, bvv, bvv, bvv};
            acc[t] = v;
        }
#pragma unroll
        for (int cs = 0; cs < 2; ++cs) {
            half8 a = *(const half8*)(apl + cs * 512 + lane * 8);
#pragma unroll
            for (int t = 0; t < 4; ++t) {
                half8 bfr = *(const half8*)(&mtl[((cs * 4 + t) << 9) + lane * 8]);
                acc[t] = mfmah(a, bfr, acc[t]);
            }
        }
#pragma unroll
        for (int t = 0; t < 4; ++t) {
            int c = t * 16 + ln;
            f32x4 o;
#pragma unroll
            for (int r = 0; r < 4; ++r) {
                short xv = Xg[(mC * 16 + qd * 4 + r) * 72 + c];
                o[r] = acc[t][r] + h2f(xv);
            }
            *reinterpret_cast<f32x4*>(out + ((size_t)b * 64 + c) * NPX + n0C + qd * 4) = o;
        }
    }
}

// ---------------------------------------------------------------------------
extern "C" void kernel_launch(void* const* d_in, const int* in_sizes, int n_in,
                              void* d_out, int out_size, void* d_ws, size_t ws_size,
                              hipStream_t stream)
{
    const float* x    = (const float*)d_in[0];
    const float* sem  = (const float*)d_in[1];
    const float* wa   = (const float*)d_in[2];
    const float* ba   = (const float*)d_in[3];
    const float* wb   = (const float*)d_in[4];
    const float* bbv  = (const float*)d_in[5];
    const float* in_w = (const float*)d_in[6];
    const float* in_b = (const float*)d_in[7];
    const float* w1   = (const float*)d_in[8];
    const float* b1   = (const float*)d_in[9];
    const float* g1   = (const float*)d_in[10];
    const float* be1  = (const float*)d_in[11];
    const float* w2   = (const float*)d_in[12];
    const float* b2   = (const float*)d_in[13];
    const float* g2   = (const float*)d_in[14];
    const float* be2  = (const float*)d_in[15];
    const float* w3   = (const float*)d_in[16];
    const float* b3   = (const float*)d_in[17];
    const float* wq   = (const float*)d_in[18];
    const float* bq   = (const float*)d_in[19];
    const float* wk   = (const float*)d_in[20];
    const float* bk   = (const float*)d_in[21];
    const float* wv   = (const float*)d_in[22];
    const float* bv   = (const float*)d_in[23];
    const float* wo   = (const float*)d_in[24];
    const float* bo   = (const float*)d_in[25];
    const float* rescale = (const float*)d_in[26];

    char* wsb = (char*)d_ws;
    short* wt   = (short*)wsb;                      // 53248 shorts
    float* gram = (float*)(wsb + (1u << 20));       // 4096 f32
    float* nsq  = gram + 4096;                      // 512 f32
    unsigned* cnt = (unsigned*)(nsq + 512);         // 2 counters (16B apart)
    float* outp = (float*)d_out;

    // zero gram + nsq + counters in one small memset (graph-capture legal)
    hipMemsetAsync(gram, 0, 4608 * sizeof(float) + 32 * sizeof(unsigned), stream);
    k_all<<<dim3(NBLK), dim3(256), 0, stream>>>(x, sem, wa, ba, wb, bbv,
                                                in_w, in_b, w1, b1, g1, be1,
                                                w2, b2, g2, be2, w3, b3,
                                                wq, bq, wk, bk, wv, bv,
                                                wo, bo, rescale,
                                                wt, gram, nsq, cnt, outp);
}

// Round 11
// 160.787 us; speedup vs baseline: 2.2323x; 2.2323x over previous
//
#include <hip/hip_runtime.h>
#include <hip/hip_bf16.h>

#define NPX 16384
typedef __attribute__((ext_vector_type(8))) short short8;
typedef __attribute__((ext_vector_type(8))) _Float16 half8;
typedef __attribute__((ext_vector_type(4))) _Float16 half4;
typedef __attribute__((ext_vector_type(4))) float f32x4;

#define DEV static __device__ __forceinline__

// wt layout (fp16 shorts), FRAGMENT-ORDERED:
// region-local idx = (cs*ET + t)*512 + lane*8 + kk
//   where e = t*16 + (lane&15), k = cs*32 + (lane>>4)*8 + kk
// so a wave's B-fragment load for (t, c0) is 1KB fully-coalesced.
#define WAB   0        // E=64  K=64   ET=4
#define WINW  4096     // E=64  K=64   ET=4
#define W1T   8192     // E=128 K=64   ET=8
#define W2T   16384    // E=128 K=128  ET=8
#define W3T   32768    // E=64  K=128  ET=4
#define WQT   40960    // E=64  K=64   ET=4
#define WKV   45056    // E=128 K=64   ET=8
#define WTOT  53248
#define NZERO 4608   // gram 4096 + nsq 512 floats zeroed by k_prep

DEV float lrelu(float v) { return v >= 0.f ? v : 0.01f * v; }
DEV short f2h(float f) { _Float16 h = (_Float16)f; return __builtin_bit_cast(short, h); }
DEV float h2f(short s) { return (float)__builtin_bit_cast(_Float16, s); }
DEV f32x4 mfmah(half8 a, half8 b, f32x4 c) {
    return __builtin_amdgcn_mfma_f32_16x16x32_f16(a, b, c, 0, 0, 0);
}

// ---------------------------------------------------------------------------
// M m-tiles (16 px each) GEMM: acc[m][t] += A[(m*16+row)][k] * W[t*16+col][k]
// A: LDS row-major, pitch shorts. WB: fragment-ordered global (ET == NT).
// ---------------------------------------------------------------------------
template<int K, int NT, int M>
DEV void gemmM(const short* __restrict__ A, int pitch,
               const short* __restrict__ WB, f32x4 (&acc)[M][NT])
{
    int lane = threadIdx.x & 63;
    int ln = lane & 15, q8 = (lane >> 4) * 8;
    const short* ap = A + (size_t)ln * pitch + q8;
    const short* bp = WB + lane * 8;
#pragma unroll
    for (int c0 = 0; c0 < K; c0 += 32) {
        half8 a[M];
#pragma unroll
        for (int m = 0; m < M; ++m)
            a[m] = *(const half8*)(ap + m * 16 * pitch + c0);
#pragma unroll
        for (int t = 0; t < NT; ++t) {
            half8 b = *(const half8*)(bp + (((c0 >> 5) * NT + t) << 9));
#pragma unroll
            for (int m = 0; m < M; ++m) acc[m][t] = mfmah(a[m], b, acc[m][t]);
        }
    }
}

template<int NT, int M>
DEV void acc_biasM(f32x4 (&acc)[M][NT], const float* __restrict__ bias)
{
    int ln = threadIdx.x & 15;
#pragma unroll
    for (int t = 0; t < NT; ++t) {
        float bv = bias[t * 16 + ln];
        f32x4 v = {bv, bv, bv, bv};
#pragma unroll
        for (int m = 0; m < M; ++m) acc[m][t] = v;
    }
}

// D layout: col=lane&15, row=(lane>>4)*4+reg -> LDS [m*16+row][pitch] fp16
template<int NT, int M>
DEV void dstoreM(const f32x4 (&acc)[M][NT], short* sD, int pitch)
{
    int lane = threadIdx.x & 63;
    int ln = lane & 15, r0 = (lane >> 4) * 4;
#pragma unroll
    for (int m = 0; m < M; ++m)
#pragma unroll
        for (int t = 0; t < NT; ++t)
#pragma unroll
            for (int r = 0; r < 4; ++r)
                sD[(m * 16 + r0 + r) * pitch + t * 16 + ln] = f2h(acc[m][t][r]);
}

// in-register LayerNorm(+lrelu) over 128 channels, per m-tile, fp32 stats
template<int NT, int M>
DEV void ln_regM(f32x4 (&acc)[M][NT], const float* __restrict__ g, const float* __restrict__ be)
{
    int lane = threadIdx.x & 63, ln = lane & 15;
#pragma unroll
    for (int m = 0; m < M; ++m) {
        f32x4 s = {0,0,0,0}, ss = {0,0,0,0};
#pragma unroll
        for (int t = 0; t < NT; ++t)
#pragma unroll
            for (int r = 0; r < 4; ++r) { float v = acc[m][t][r]; s[r] += v; ss[r] += v * v; }
#pragma unroll
        for (int off = 1; off < 16; off <<= 1)
#pragma unroll
            for (int r = 0; r < 4; ++r) {
                s[r] += __shfl_xor(s[r], off);
                ss[r] += __shfl_xor(ss[r], off);
            }
        f32x4 mm, rs;
#pragma unroll
        for (int r = 0; r < 4; ++r) {
            float mean = s[r] * (1.f / 128.f);
            float var = ss[r] * (1.f / 128.f) - mean * mean;
            mm[r] = mean; rs[r] = rsqrtf(var + 1e-5f);
        }
#pragma unroll
        for (int t = 0; t < NT; ++t) {
            float gg = g[t * 16 + ln], bb = be[t * 16 + ln];
#pragma unroll
            for (int r = 0; r < 4; ++r)
                acc[m][t][r] = lrelu((acc[m][t][r] - mm[r]) * rs[r] * gg + bb);
        }
    }
}

// ---------------------------------------------------------------------------
// k_prep: fragment-ordered fp16 weights; also zeroes gram+nsq.
// ---------------------------------------------------------------------------
__global__ __launch_bounds__(256) void k_prep(const float* __restrict__ wa,
                                              const float* __restrict__ wb,
                                              const float* __restrict__ in_w,
                                              const float* __restrict__ w1,
                                              const float* __restrict__ w2,
                                              const float* __restrict__ w3,
                                              const float* __restrict__ wq,
                                              const float* __restrict__ wk,
                                              const float* __restrict__ wv,
                                              short* __restrict__ wt,
                                              float* __restrict__ gz)
{
    int idx = blockIdx.x * 256 + threadIdx.x;
    if (idx >= WTOT) {
        int z = idx - WTOT;
        if (z < NZERO) gz[z] = 0.f;
        return;
    }
    // region decode
    int base, ETl;
    if      (idx < WINW) { base = WAB;  ETl = 4; }
    else if (idx < W1T)  { base = WINW; ETl = 4; }
    else if (idx < W2T)  { base = W1T;  ETl = 8; }
    else if (idx < W3T)  { base = W2T;  ETl = 8; }
    else if (idx < WQT)  { base = W3T;  ETl = 4; }
    else if (idx < WKV)  { base = WQT;  ETl = 4; }
    else                 { base = WKV;  ETl = 8; }
    int i = idx - base;
    int frag = i >> 9, wi = i & 511;
    int lane = wi >> 3, kk = wi & 7;
    int ln = lane & 15, qd = lane >> 4;
    int cs = frag / ETl, t = frag % ETl;
    int e = t * 16 + ln;
    int k = cs * 32 + qd * 8 + kk;
    float v;
    if (base == WAB) {
        v = (e < 4) ? wa[k * 4 + e] : wb[((e - 4) / 3) * 192 + k * 3 + ((e - 4) % 3)];
    } else if (base == WINW) {
        v = in_w[k * 64 + e];
    } else if (base == W1T) {
        v = w1[k * 128 + e];
    } else if (base == W2T) {
        v = w2[k * 128 + e];
    } else if (base == W3T) {
        v = w3[k * 64 + e];
    } else if (base == WQT) {
        v = wq[k * 64 + e];
    } else {
        v = (e < 64) ? wk[k * 64 + e] : wv[k * 64 + (e - 64)];
    }
    wt[idx] = f2h(v);
}

// ---------------------------------------------------------------------------
// k_main: path-split fused kernel. 1024 blocks x 256 thr (4 waves).
// 2 px-groups of 32 px per block; per group: wave role0 = MLP path,
// role1 = feature path; paths join at gram via LDS.
// Per-group LDS [8960 shorts]: X[32][72] | T[32][72] | H[32][136]
//   KT[64][32] overlays X (dead after phase 1);
//   v-frag staging (2048 sh) then scr (1152 f32) overlay T.
// xm and v go to global in FRAGMENT order (coalesced); xm also->H for q GEMM.
// ---------------------------------------------------------------------------
__global__ __launch_bounds__(256, 4) void k_main(const float* __restrict__ x,
                                                 const float* __restrict__ sem,
                                                 const float* __restrict__ ba,
                                                 const float* __restrict__ bbv,
                                                 const float* __restrict__ in_b,
                                                 const float* __restrict__ b1,
                                                 const float* __restrict__ g1,
                                                 const float* __restrict__ be1,
                                                 const float* __restrict__ b2,
                                                 const float* __restrict__ g2,
                                                 const float* __restrict__ be2,
                                                 const float* __restrict__ b3,
                                                 const float* __restrict__ bq,
                                                 const float* __restrict__ bk,
                                                 const float* __restrict__ bv,
                                                 const short* __restrict__ wt,
                                                 short* __restrict__ vfrag,
                                                 short* __restrict__ xmfrag,
                                                 float* __restrict__ gram,
                                                 float* __restrict__ nsq)
{
    __shared__ short blob[2][8960];
    const int tid = threadIdx.x, w = tid >> 6, lane = tid & 63;
    const int ln = lane & 15, qd = lane >> 4, r0 = qd * 4;
    const int g = w & 1, role = w >> 1;
    const int pw = blockIdx.x * 64 + g * 32;
    const int b = pw >> 14, n0 = pw & (NPX - 1);
    const float* xb = x + (size_t)b * 64 * NPX;
    short* X  = blob[g];            // [32][72] = 2304
    short* T  = blob[g] + 2304;     // [32][72] = 2304
    short* H  = blob[g] + 4608;     // [32][136] = 4352
    short* KT = X;                  // [64][32] = 2048 (after s2)
    float* scr = (float*)T;         // 1152 f32 (after v-frag copy)

    // ---- stage: each role stages its 16-px half of the 32-px x tile ----
    {
        float vb[16];
#pragma unroll
        for (int t = 0; t < 16; ++t)
            vb[t] = xb[(size_t)(qd * 16 + t) * NPX + n0 + role * 16 + ln];
        short8 lo, hi;
#pragma unroll
        for (int t = 0; t < 8; ++t) { lo[t] = f2h(vb[t]); hi[t] = f2h(vb[8 + t]); }
        *reinterpret_cast<short8*>(&X[(role * 16 + ln) * 72 + qd * 16]) = lo;
        *reinterpret_cast<short8*>(&X[(role * 16 + ln) * 72 + qd * 16 + 8]) = hi;
    }
    __syncthreads();   // s1: X staged

    // ---- phase 1: both roles consume X ----
    f32x4 acc8[2][8];          // role0: h1/h2 accumulator (lives through phase 2)
    if (role == 0) {
        acc_biasM<8, 2>(acc8, b1);
        gemmM<64, 8, 2>(X, 72, wt + W1T, acc8);
    } else {
        f32x4 a1f[2][4];
        {
            f32x4 z = {0,0,0,0};
#pragma unroll
            for (int m = 0; m < 2; ++m)
#pragma unroll
                for (int t = 0; t < 4; ++t) a1f[m][t] = z;
        }
        gemmM<64, 4, 2>(X, 72, wt + WAB, a1f);
        // mask + bias -> T (feat tile)
#pragma unroll
        for (int t = 0; t < 4; ++t) {
            int j = t * 16 + ln;
            int cls = (j < 4) ? 0 : 1 + (j - 4) / 3;
            float bias = (j < 4) ? ba[j] : bbv[j - 4];
#pragma unroll
            for (int m = 0; m < 2; ++m) {
                f32x4 sm4 = *(const f32x4*)(sem + ((size_t)b * 21 + cls) * NPX + n0 + m * 16 + r0);
#pragma unroll
                for (int r = 0; r < 4; ++r)
                    T[(m * 16 + r0 + r) * 72 + j] = f2h(fmaxf(sm4[r], 0.f) * a1f[m][t][r] + bias);
            }
        }
    }
    __syncthreads();   // s2: X reads done everywhere -> KT may overwrite X

    // ---- phase 2: role-private pipelines ----
    f32x4 aqreg[2][4];         // role0: q result, consumed by gram in phase 3
    if (role == 0) {
        ln_regM<8, 2>(acc8, g1, be1);
        dstoreM<8, 2>(acc8, H, 136);
        acc_biasM<8, 2>(acc8, b2);
        gemmM<128, 8, 2>(H, 136, wt + W2T, acc8);
        ln_regM<8, 2>(acc8, g2, be2);
        dstoreM<8, 2>(acc8, H, 136);
        f32x4 a4[2][4];
        acc_biasM<4, 2>(a4, b3);
        gemmM<128, 4, 2>(H, 136, wt + W3T, a4);
        // xm: direct coalesced fragment store (element (p,c) at
        // tile*1024 + ((p&12)<<2 | (c&15))*16 + (c>>4)*4 + (p&3))
#pragma unroll
        for (int m = 0; m < 2; ++m) {
            short8 lo, hi;
#pragma unroll
            for (int i = 0; i < 8; ++i) {
                lo[i] = f2h(a4[m][i >> 2][i & 3]);          // t=0..1
                hi[i] = f2h(a4[m][2 + (i >> 2)][i & 3]);    // t=2..3
            }
            size_t xbase = ((size_t)(pw >> 4) + m) * 1024 + lane * 16;
            *reinterpret_cast<short8*>(xmfrag + xbase) = lo;
            *reinterpret_cast<short8*>(xmfrag + xbase + 8) = hi;
        }
        dstoreM<4, 2>(a4, H, 72);                    // xm tile for q GEMM
        acc_biasM<4, 2>(aqreg, bq);
        gemmM<64, 4, 2>(H, 72, wt + WQT, aqreg);
    } else {
        f32x4 a4[2][4];
        acc_biasM<4, 2>(a4, in_b);
        gemmM<64, 4, 2>(T, 72, wt + WINW, a4);
        dstoreM<4, 2>(a4, T, 72);                    // y overwrites feat
        f32x4 a3[2][8];
#pragma unroll
        for (int t = 0; t < 8; ++t) {
            float bvv = (t < 4) ? bk[t * 16 + ln] : bv[(t - 4) * 16 + ln];
            f32x4 vv = {bvv, bvv, bvv, bvv};
            a3[0][t] = vv; a3[1][t] = vv;
        }
        gemmM<64, 8, 2>(T, 72, wt + WKV, a3);
        // k -> KT (ch-major, LDS)
#pragma unroll
        for (int t = 0; t < 4; ++t)
#pragma unroll
            for (int m = 0; m < 2; ++m)
#pragma unroll
                for (int r = 0; r < 4; ++r)
                    KT[(t * 16 + ln) * 32 + m * 16 + r0 + r] = f2h(a3[m][t][r]);
        // v -> T in A-fragment order, then coalesced copy to global
#pragma unroll
        for (int t = 4; t < 8; ++t)
#pragma unroll
            for (int m = 0; m < 2; ++m)
#pragma unroll
                for (int r = 0; r < 4; ++r)
                    T[m * 1024 + ((t - 4) >> 1) * 512 +
                      ((((t - 4) & 1) * 2 + (ln >> 3)) & 3) * 128 +
                      (r0 + r) * 8 + (ln & 7)] = f2h(a3[m][t][r]);
#pragma unroll
        for (int it = 0; it < 4; ++it) {
            short8 vv = *(const short8*)(&T[it * 512 + lane * 8]);
            *reinterpret_cast<short8*>(vfrag + ((size_t)(pw >> 4)) * 1024 + it * 512 + lane * 8) = vv;
        }
        // kk gram partial from regs -> scr[0..64) (T front, after v copy)
#pragma unroll
        for (int h = 0; h < 4; ++h) {
            f32x4 akk = {0, 0, 0, 0};
#pragma unroll
            for (int m = 0; m < 2; ++m) {
                half8 ka8 = {0, 0, 0, 0, 0, 0, 0, 0};
#pragma unroll
                for (int r = 0; r < 4; ++r) ka8[r] = (_Float16)a3[m][h][r];
                akk = mfmah(ka8, ka8, akk);
            }
#pragma unroll
            for (int r = 0; r < 4; ++r)
                if (ln == r0 + r) scr[h * 16 + r0 + r] = akk[r];
        }
    }
    __syncthreads();   // s3: KT + kk + v-copy done; scr[64..) writable

    // ---- phase 3: gram (role0; q from regs, k from KT) ----
    if (role == 0) {
#pragma unroll
        for (int h = 0; h < 4; ++h) {
            f32x4 aqk = {0,0,0,0}, aqq = {0,0,0,0};
#pragma unroll
            for (int m = 0; m < 2; ++m) {
                half4 kv4 = *(const half4*)(&KT[(h * 16 + ln) * 32 + m * 16 + r0]);
                half8 qa8 = {0, 0, 0, 0, 0, 0, 0, 0};
                half8 ka8 = {0, 0, 0, 0, 0, 0, 0, 0};
#pragma unroll
                for (int r = 0; r < 4; ++r) {
                    qa8[r] = (_Float16)aqreg[m][h][r];
                    ka8[r] = kv4[r];
                }
                aqk = mfmah(qa8, ka8, aqk);
                aqq = mfmah(qa8, qa8, aqq);
            }
#pragma unroll
            for (int r = 0; r < 4; ++r) {
                int d = r0 + r;
                scr[64 + h * 256 + d * 16 + ln] = aqk[r];
                if (ln == d) scr[1088 + h * 16 + d] = aqq[r];
            }
        }
    }
    __syncthreads();   // s4: scratch complete

    // ---- cross-group reduce + atomics ----
    const float* s0 = (const float*)(blob[0] + 2304);
    const float* s1 = (const float*)(blob[1] + 2304);
#pragma unroll
    for (int i = 0; i < 4; ++i) {
        int idx = i * 256 + tid;
        atomicAdd(&gram[(size_t)b * 1024 + idx], s0[64 + idx] + s1[64 + idx]);
    }
    if (tid < 64) {
        atomicAdd(&nsq[b * 64 + tid], s0[1088 + tid] + s1[1088 + tid]);
    } else if (tid < 128) {
        int t2 = tid - 64;
        atomicAdd(&nsq[256 + b * 64 + t2], s0[t2] + s1[t2]);
    }
}

// ---------------------------------------------------------------------------
// k_attnM: softmax + fold wo -> MT in B-fragment order for k_out
// element (e=cc, k=he): b*4096 + ((he>>5)*4 + (cc>>4))*512
//                       + ((he>>3)&3)*128 + (cc&15)*8 + (he&7)
// ---------------------------------------------------------------------------
__global__ __launch_bounds__(256) void k_attnM(const float* __restrict__ gram,
                                               const float* __restrict__ nsq,
                                               const float* __restrict__ rescale,
                                               const float* __restrict__ wo,
                                               short* __restrict__ MT)
{
    __shared__ float s_at[1024];
    int b = blockIdx.x, tid = threadIdx.x;
    if (tid < 64) {
        int h = tid >> 4, d = tid & 15;
        float nq = sqrtf(nsq[b * 64 + h * 16 + d]) + 1e-8f;
        float rsc = rescale[h];
        float lg[16];
#pragma unroll
        for (int e = 0; e < 16; ++e) {
            float nk = sqrtf(nsq[256 + b * 64 + h * 16 + e]) + 1e-8f;
            lg[e] = rsc * gram[b * 1024 + h * 256 + d * 16 + e] / (nq * nk);
        }
        float m = lg[0];
#pragma unroll
        for (int e = 1; e < 16; ++e) m = fmaxf(m, lg[e]);
        float ssum = 0.f;
#pragma unroll
        for (int e = 0; e < 16; ++e) { lg[e] = expf(lg[e] - m); ssum += lg[e]; }
        float inv = 1.f / ssum;
#pragma unroll
        for (int e = 0; e < 16; ++e) s_at[h * 256 + d * 16 + e] = lg[e] * inv;
    }
    __syncthreads();
    int he = tid >> 2, h = he >> 4, e = he & 15;
    int cc0 = (tid & 3) * 16;
    int mbase = b * 4096 + (he >> 5) * 2048 + ((he >> 3) & 3) * 128 + (he & 7);
#pragma unroll
    for (int cx = 0; cx < 16; ++cx) {
        int cc = cc0 + cx;
        float s = 0.f;
#pragma unroll
        for (int d = 0; d < 16; ++d)
            s = fmaf(s_at[h * 256 + d * 16 + e], wo[(h * 16 + d) * 64 + cc], s);
        MT[mbase + (cc >> 4) * 512 + (cc & 15) * 8] = f2h(s);
    }
}

// ---------------------------------------------------------------------------
// k_out: out = v@M + bo + xm  (fully coalesced: vfrag A, MT B, xmfrag resid)
// ---------------------------------------------------------------------------
__global__ __launch_bounds__(256) void k_out(const short* __restrict__ vfrag,
                                             const short* __restrict__ xmfrag,
                                             const short* __restrict__ MT,
                                             const float* __restrict__ bo,
                                             float* __restrict__ out)
{
    int tid = threadIdx.x, w = tid >> 6, lane = tid & 63;
    int ln = lane & 15, qd = lane >> 4;
    int pw = blockIdx.x * 64 + w * 16;
    int b = pw >> 14, n0 = pw & (NPX - 1);
    size_t tile = (size_t)(pw >> 4);

    f32x4 acc[4];
    {
#pragma unroll
        for (int t = 0; t < 4; ++t) {
            float bv = bo[t * 16 + ln];
            f32x4 v = {bv, bv, bv, bv};
            acc[t] = v;
        }
    }
    const short* ap = vfrag + tile * 1024 + lane * 8;
    const short* bp = MT + b * 4096 + lane * 8;
#pragma unroll
    for (int cs = 0; cs < 2; ++cs) {
        half8 a = *(const half8*)(ap + cs * 512);
#pragma unroll
        for (int t = 0; t < 4; ++t) {
            half8 bfr = *(const half8*)(bp + ((cs * 4 + t) << 9));
            acc[t] = mfmah(a, bfr, acc[t]);
        }
    }
    short8 x0 = *(const short8*)(xmfrag + tile * 1024 + lane * 16);
    short8 x1 = *(const short8*)(xmfrag + tile * 1024 + lane * 16 + 8);
#pragma unroll
    for (int t = 0; t < 4; ++t) {
        int c = t * 16 + ln;
        f32x4 o;
#pragma unroll
        for (int r = 0; r < 4; ++r) {
            short xv = (t < 2) ? x0[t * 4 + r] : x1[(t - 2) * 4 + r];
            o[r] = acc[t][r] + h2f(xv);
        }
        *reinterpret_cast<f32x4*>(out + ((size_t)b * 64 + c) * NPX + n0 + qd * 4) = o;
    }
}

// ---------------------------------------------------------------------------
extern "C" void kernel_launch(void* const* d_in, const int* in_sizes, int n_in,
                              void* d_out, int out_size, void* d_ws, size_t ws_size,
                              hipStream_t stream)
{
    const float* x    = (const float*)d_in[0];
    const float* sem  = (const float*)d_in[1];
    const float* wa   = (const float*)d_in[2];
    const float* ba   = (const float*)d_in[3];
    const float* wb   = (const float*)d_in[4];
    const float* bbv  = (const float*)d_in[5];
    const float* in_w = (const float*)d_in[6];
    const float* in_b = (const float*)d_in[7];
    const float* w1   = (const float*)d_in[8];
    const float* b1   = (const float*)d_in[9];
    const float* g1   = (const float*)d_in[10];
    const float* be1  = (const float*)d_in[11];
    const float* w2   = (const float*)d_in[12];
    const float* b2   = (const float*)d_in[13];
    const float* g2   = (const float*)d_in[14];
    const float* be2  = (const float*)d_in[15];
    const float* w3   = (const float*)d_in[16];
    const float* b3   = (const float*)d_in[17];
    const float* wq   = (const float*)d_in[18];
    const float* bq   = (const float*)d_in[19];
    const float* wk   = (const float*)d_in[20];
    const float* bk   = (const float*)d_in[21];
    const float* wv   = (const float*)d_in[22];
    const float* bv   = (const float*)d_in[23];
    const float* wo   = (const float*)d_in[24];
    const float* bo   = (const float*)d_in[25];
    const float* rescale = (const float*)d_in[26];

    char* wsb = (char*)d_ws;
    short* wt   = (short*)wsb;                                 // 53248 shorts
    short* vpx  = (short*)(wsb + (1u << 20));                  // 8 MB v fragment-order
    short* xmp  = (short*)(wsb + (1u << 20) + (8u << 20));     // 8 MB xm fragment-order
    float* gram = (float*)(wsb + (1u << 20) + (16u << 20));    // 4096 f32
    float* nsq  = gram + 4096;                                 // 512 f32
    short* MT   = (short*)(nsq + 512);                         // 16384 shorts

    dim3 blk(256);
    k_prep<<<dim3(226), blk, 0, stream>>>(wa, wb, in_w, w1, w2, w3, wq, wk, wv, wt, gram);
    k_main<<<dim3(1024), blk, 0, stream>>>(x, sem, ba, bbv, in_b,
                                           b1, g1, be1, b2, g2, be2, b3, bq, bk, bv,
                                           wt, vpx, xmp, gram, nsq);
    k_attnM<<<dim3(4), blk, 0, stream>>>(gram, nsq, rescale, wo, MT);
    k_out<<<dim3(1024), blk, 0, stream>>>(vpx, xmp, MT, bo, (float*)d_out);
}